// Round 1
// baseline (525.207 us; speedup 1.0000x reference)
//
#include <hip/hip_runtime.h>

#define L_SIG 3000
#define NB 8
#define CIN 64
#define COUT 128
#define KW 25
#define TOUT 2976
#define FMAXB 973   // frequency bins used: 0..972

// ws float offsets
#define S_OFF   0
#define S_LEN   996352      // 8*973*64*2
#define WC_OFF  996352
#define WC_LEN  3312640     // sum bins*n_o*64*2
#define X_OFF   4308992
#define X_LEN   414080

__device__ __forceinline__ void build_roots(float2* rootsL) {
    // rootsL[k] = (cos(2pi k/3000), -sin(2pi k/3000)) = e^{-2pi i k/3000}
    for (int k = threadIdx.x; k < L_SIG; k += blockDim.x) {
        float s, c;
        __sincosf((float)k * 0.00209439510239319549f, &s, &c);
        rootsL[k] = make_float2(c, -s);
    }
}

// ---------------- K1: signal forward DFT (bins 0..972) -----------------
// S[b][f][i][2] ; one block = one row (b,i), 256 f per block
__global__ __launch_bounds__(256) void k_sig_dft(const float* __restrict__ sig,
                                                 float* __restrict__ S) {
    __shared__ float2 rootsL[L_SIG];
    __shared__ float sigL[L_SIG];
    int row = blockIdx.x;                       // b*64+i
    int f = blockIdx.y * 256 + threadIdx.x;
    build_roots(rootsL);
    const float* srow = sig + (size_t)row * L_SIG;
    for (int n = threadIdx.x; n < L_SIG; n += 256) sigL[n] = srow[n];
    __syncthreads();
    if (f >= FMAXB) return;
    float accR = 0.f, accI = 0.f;
    unsigned idx = 0;
    #pragma unroll 4
    for (int n = 0; n < L_SIG; ++n) {
        float s = sigL[n];
        float2 r = rootsL[idx];
        accR = fmaf(s, r.x, accR);
        accI = fmaf(s, r.y, accI);
        unsigned t = idx + (unsigned)f;
        idx = min(t, t - 3000u);
    }
    int b = row >> 6, i = row & 63;
    size_t o = (((size_t)b * FMAXB + f) * 64 + i) * 2;
    S[o] = accR; S[o + 1] = accI;
}

// ---------------- K2: weight DFT (conj) per band -----------------------
// Wc (per band g): [f_local][o_local][i][2]
__global__ __launch_bounds__(256) void k_w_dft(const float* __restrict__ w,
                                               float* __restrict__ Wc) {
    __shared__ float2 rootsL[L_SIG];
    __shared__ float wL[CIN * KW];
    const int startv[5] = {0,122,244,366,488};
    const int binsv[5]  = {123,123,123,123,485};
    const int n_ov[5]   = {25,25,25,25,28};
    const size_t wbase[5] = {0, 393600, 787200, 1180800, 1574400};
    int o = blockIdx.x;
    int band = min(o / 25, 4);
    int o_local = o - band * 25;
    int bins = binsv[band];
    int f = blockIdx.y * 256 + threadIdx.x;
    build_roots(rootsL);
    const float* wrow = w + (size_t)o * CIN * KW;
    for (int k = threadIdx.x; k < CIN * KW; k += 256) wL[k] = wrow[k];
    __syncthreads();
    if (f >= bins) return;
    int n_o = n_ov[band];
    unsigned fg = (unsigned)(startv[band] + f);
    float* outp = Wc + wbase[band] + (((size_t)f * n_o + o_local) * 64) * 2;
    for (int i = 0; i < CIN; ++i) {
        float ar = 0.f, ai = 0.f;
        unsigned idx = 0;
        const float* wi = wL + i * KW;
        #pragma unroll
        for (int t = 0; t < KW; ++t) {
            float2 r = rootsL[idx];
            float wv = wi[t];
            ar = fmaf(wv, r.x, ar);
            ai = fmaf(wv, -r.y, ai);      // +sin component
            unsigned a = idx + fg;
            idx = min(a, a - 3000u);
        }
        outp[i * 2] = ar; outp[i * 2 + 1] = ai;
    }
}

// ---------------- K3: per-bin mix  X = sum_i S * Wc --------------------
// X (per band g): [o_local][f_local][b][2]
__global__ __launch_bounds__(256) void k_mix(const float* __restrict__ S,
                                             const float* __restrict__ Wc,
                                             float* __restrict__ X) {
    const int startv[5] = {0,122,244,366,488};
    const int binsv[5]  = {123,123,123,123,485};
    const int n_ov[5]   = {25,25,25,25,28};
    const size_t wbase[5] = {0, 393600, 787200, 1180800, 1574400};
    const size_t xbase[5] = {0, 49200, 98400, 147600, 196800};
    const int cum[6] = {0, 24600, 49200, 73800, 98400, 207040};
    int gid = blockIdx.x * 256 + threadIdx.x;
    if (gid >= 207040) return;
    int band = 0;
    while (gid >= cum[band + 1]) band++;
    int r = gid - cum[band];
    int b = r & 7;
    int t2 = r >> 3;
    int bins = binsv[band];
    int f_local = t2 % bins;
    int o_local = t2 / bins;
    int n_o = n_ov[band];
    int fg = startv[band] + f_local;
    const float* sp = S + (((size_t)b * FMAXB + fg) * 64) * 2;
    const float* wp = Wc + wbase[band] + (((size_t)f_local * n_o + o_local) * 64) * 2;
    float xr = 0.f, xi = 0.f;
    #pragma unroll 8
    for (int i = 0; i < CIN; ++i) {
        float sr = sp[i * 2], si = sp[i * 2 + 1];
        float wr = wp[i * 2], wi = wp[i * 2 + 1];
        xr = fmaf(sr, wr, xr); xr = fmaf(-si, wi, xr);
        xi = fmaf(sr, wi, xi); xi = fmaf(si, wr, xi);
    }
    float* xp = X + xbase[band] + (((size_t)o_local * bins + f_local) * 8 + b) * 2;
    xp[0] = xr; xp[1] = xi;
}

// ---------------- K4: inverse DFT (band-limited) + bias ----------------
__global__ __launch_bounds__(256) void k_idft(const float* __restrict__ X,
                                              const float* __restrict__ bias,
                                              float* __restrict__ out) {
    __shared__ float2 rootsL[L_SIG];
    __shared__ float XL[485 * 16];   // [f_local][b][2], pre-scaled
    const int startv[5] = {0,122,244,366,488};
    const int binsv[5]  = {123,123,123,123,485};
    const size_t xbase[5] = {0, 49200, 98400, 147600, 196800};
    int o = blockIdx.x;
    int band = min(o / 25, 4);
    int o_local = o - band * 25;
    int bins = binsv[band];
    int start = startv[band];
    build_roots(rootsL);
    const float* xp = X + xbase[band] + (size_t)o_local * bins * 16;
    const float inv = 1.0f / 3000.0f;
    for (int k = threadIdx.x; k < bins * 16; k += 256) {
        int f_local = k >> 4;
        float scale = ((start + f_local) == 0) ? inv : 2.0f * inv;
        XL[k] = xp[k] * scale;
    }
    __syncthreads();
    int t = blockIdx.y * 256 + threadIdx.x;
    if (t >= TOUT) return;
    float acc[NB] = {0.f,0.f,0.f,0.f,0.f,0.f,0.f,0.f};
    unsigned idx = ((unsigned)start * (unsigned)t) % 3000u;
    for (int fl = 0; fl < bins; ++fl) {
        float2 r = rootsL[idx];
        const float* xf = XL + fl * 16;
        #pragma unroll
        for (int b = 0; b < NB; ++b) {
            // Xr*cos - Xi*sin  ==  Xr*r.x + Xi*r.y   (r.y = -sin)
            acc[b] = fmaf(xf[b * 2], r.x, acc[b]);
            acc[b] = fmaf(xf[b * 2 + 1], r.y, acc[b]);
        }
        unsigned a = idx + (unsigned)t;
        idx = min(a, a - 3000u);
    }
    float bv = bias[o];
    #pragma unroll
    for (int b = 0; b < NB; ++b) {
        out[((size_t)b * COUT + o) * TOUT + t] = acc[b] + bv;
    }
}

extern "C" void kernel_launch(void* const* d_in, const int* in_sizes, int n_in,
                              void* d_out, int out_size, void* d_ws, size_t ws_size,
                              hipStream_t stream) {
    const float* sig  = (const float*)d_in[0];   // (8,64,3000) f32
    const float* w    = (const float*)d_in[1];   // (128,64,25) f32
    const float* bias = (const float*)d_in[2];   // (128,) f32
    // fb1..fb5 (d_in[3..7]) are analytically-known DFT bases: unused.
    float* out = (float*)d_out;
    float* ws  = (float*)d_ws;
    float* S  = ws + S_OFF;
    float* Wc = ws + WC_OFF;
    float* X  = ws + X_OFF;

    k_sig_dft<<<dim3(512, 4), 256, 0, stream>>>(sig, S);
    k_w_dft  <<<dim3(128, 2), 256, 0, stream>>>(w, Wc);
    k_mix    <<<dim3(809),    256, 0, stream>>>(S, Wc, X);
    k_idft   <<<dim3(128, 12),256, 0, stream>>>(X, bias, out);
}

// Round 2
// 281.987 us; speedup vs baseline: 1.8625x; 1.8625x over previous
//
#include <hip/hip_runtime.h>

#define L_SIG 3000
#define NB 8
#define CIN 64
#define COUT 128
#define KW 25
#define TOUT 2976
#define FMAXB 973   // frequency bins used: 0..972

// ws float offsets
#define S_OFF   0
#define S_LEN   996352      // 8*64*973*2   S[b][i][f][2]
#define WC_OFF  996352
#define WC_LEN  3312640     // sum bins*n_o*64*2
#define X_OFF   4308992
#define X_LEN   414080

#define TWO_PI_OVER_L 0.00209439510239319549f

// ---------------- K1: signal forward DFT (bins 0..972) -----------------
// 4 rows per block, 256 f per block. Roots via in-register complex
// recurrence r <- r * e^{-2pi i f / 3000} (no LDS table, no conflicts).
// S layout: [b][i][f][2]  -> coalesced stores across lanes (f fastest).
__global__ __launch_bounds__(256) void k_sig_dft(const float* __restrict__ sig,
                                                 float* __restrict__ S) {
    __shared__ float sigL[L_SIG][4];     // [n][row]  48 KB
    int rg = blockIdx.x;                 // row group: rows 4*rg .. 4*rg+3
    int f = blockIdx.y * 256 + threadIdx.x;
    int row0 = rg * 4;

    // stage 4 rows, transposed to [n][r]
    for (int r = 0; r < 4; ++r) {
        const float* srow = sig + (size_t)(row0 + r) * L_SIG;
        for (int n4 = threadIdx.x; n4 < L_SIG / 4; n4 += 256) {
            float4 v = ((const float4*)srow)[n4];
            int n = n4 * 4;
            sigL[n + 0][r] = v.x;
            sigL[n + 1][r] = v.y;
            sigL[n + 2][r] = v.z;
            sigL[n + 3][r] = v.w;
        }
    }
    __syncthreads();

    // w = e^{-2pi i f/3000}
    float ws, wc;
    __sincosf((float)f * TWO_PI_OVER_L, &ws, &wc);
    float wr = wc, wi = -ws;
    float rr = 1.0f, ri = 0.0f;          // r = e^{-2pi i f n/3000} at n=0

    float aR0 = 0.f, aI0 = 0.f, aR1 = 0.f, aI1 = 0.f;
    float aR2 = 0.f, aI2 = 0.f, aR3 = 0.f, aI3 = 0.f;

    #pragma unroll 4
    for (int n = 0; n < L_SIG; ++n) {
        float4 sv = *(const float4*)(&sigL[n][0]);   // broadcast b128
        aR0 = fmaf(sv.x, rr, aR0);  aI0 = fmaf(sv.x, ri, aI0);
        aR1 = fmaf(sv.y, rr, aR1);  aI1 = fmaf(sv.y, ri, aI1);
        aR2 = fmaf(sv.z, rr, aR2);  aI2 = fmaf(sv.z, ri, aI2);
        aR3 = fmaf(sv.w, rr, aR3);  aI3 = fmaf(sv.w, ri, aI3);
        float nr = fmaf(-ri, wi, rr * wr);
        float ni = fmaf( ri, wr, rr * wi);
        rr = nr; ri = ni;
    }

    if (f >= FMAXB) return;
    int b = row0 >> 6, i0 = row0 & 63;
    // S[b][i][f][2]
    size_t base = (((size_t)b * 64 + i0) * FMAXB + f) * 2;
    S[base]                 = aR0; S[base + 1]                 = aI0;
    S[base + 2 * FMAXB]     = aR1; S[base + 2 * FMAXB + 1]     = aI1;
    S[base + 4 * FMAXB]     = aR2; S[base + 4 * FMAXB + 1]     = aI2;
    S[base + 6 * FMAXB]     = aR3; S[base + 6 * FMAXB + 1]     = aI3;
}

// ---------------- K2: weight DFT (conj) per band -----------------------
// Wc (per band g): [f_local][o_local][i][2]
__global__ __launch_bounds__(256) void k_w_dft(const float* __restrict__ w,
                                               float* __restrict__ Wc) {
    __shared__ float wL[CIN * KW];
    const int startv[5] = {0,122,244,366,488};
    const int binsv[5]  = {123,123,123,123,485};
    const int n_ov[5]   = {25,25,25,25,28};
    const size_t wbase[5] = {0, 393600, 787200, 1180800, 1574400};
    int o = blockIdx.x;
    int band = min(o / 25, 4);
    int o_local = o - band * 25;
    int bins = binsv[band];
    int f = blockIdx.y * 256 + threadIdx.x;
    const float* wrow = w + (size_t)o * CIN * KW;
    for (int k = threadIdx.x; k < CIN * KW; k += 256) wL[k] = wrow[k];
    __syncthreads();
    if (f >= bins) return;
    int n_o = n_ov[band];
    int fg = startv[band] + f;
    // conj roots: e^{+2pi i fg t/3000}; recurrence over t (25 steps)
    float ws_, wc_;
    __sincosf((float)fg * TWO_PI_OVER_L, &ws_, &wc_);
    float wr = wc_, wi = ws_;    // +sin
    float* outp = Wc + wbase[band] + (((size_t)f * n_o + o_local) * 64) * 2;
    for (int i = 0; i < CIN; ++i) {
        float ar = 0.f, ai = 0.f;
        float rr = 1.0f, ri = 0.0f;
        const float* wv = wL + i * KW;
        #pragma unroll
        for (int t = 0; t < KW; ++t) {
            float x = wv[t];
            ar = fmaf(x, rr, ar);
            ai = fmaf(x, ri, ai);
            float nr = fmaf(-ri, wi, rr * wr);
            float ni = fmaf( ri, wr, rr * wi);
            rr = nr; ri = ni;
        }
        outp[i * 2] = ar; outp[i * 2 + 1] = ai;
    }
}

// ---------------- K3: per-bin mix  X = sum_i S * Wc --------------------
// X (per band g): [o_local][f_local][b][2] ; S is [b][i][f][2]
__global__ __launch_bounds__(256) void k_mix(const float* __restrict__ S,
                                             const float* __restrict__ Wc,
                                             float* __restrict__ X) {
    const int startv[5] = {0,122,244,366,488};
    const int binsv[5]  = {123,123,123,123,485};
    const int n_ov[5]   = {25,25,25,25,28};
    const size_t wbase[5] = {0, 393600, 787200, 1180800, 1574400};
    const size_t xbase[5] = {0, 49200, 98400, 147600, 196800};
    const int cum[6] = {0, 24600, 49200, 73800, 98400, 207040};
    int gid = blockIdx.x * 256 + threadIdx.x;
    if (gid >= 207040) return;
    int band = 0;
    while (gid >= cum[band + 1]) band++;
    int r = gid - cum[band];
    int b = r & 7;
    int t2 = r >> 3;
    int bins = binsv[band];
    int f_local = t2 % bins;
    int o_local = t2 / bins;
    int n_o = n_ov[band];
    int fg = startv[band] + f_local;
    const float* sp = S + (((size_t)b * 64) * FMAXB + fg) * 2;
    const float* wp = Wc + wbase[band] + (((size_t)f_local * n_o + o_local) * 64) * 2;
    float xr = 0.f, xi = 0.f;
    #pragma unroll 8
    for (int i = 0; i < CIN; ++i) {
        float sr = sp[i * 2 * FMAXB], si = sp[i * 2 * FMAXB + 1];
        float wr = wp[i * 2], wi = wp[i * 2 + 1];
        xr = fmaf(sr, wr, xr); xr = fmaf(-si, wi, xr);
        xi = fmaf(sr, wi, xi); xi = fmaf(si, wr, xi);
    }
    float* xp = X + xbase[band] + (((size_t)o_local * bins + f_local) * 8 + b) * 2;
    xp[0] = xr; xp[1] = xi;
}

// ---------------- K4: inverse DFT (band-limited) + bias ----------------
// One block per (o, t-group). Roots via register recurrence over f.
__global__ __launch_bounds__(256) void k_idft(const float* __restrict__ X,
                                              const float* __restrict__ bias,
                                              float* __restrict__ out) {
    __shared__ float XL[485 * 16];   // [f_local][b][2], pre-scaled
    const int startv[5] = {0,122,244,366,488};
    const int binsv[5]  = {123,123,123,123,485};
    const size_t xbase[5] = {0, 49200, 98400, 147600, 196800};
    int o = blockIdx.x;
    int band = min(o / 25, 4);
    int o_local = o - band * 25;
    int bins = binsv[band];
    int start = startv[band];
    const float* xp = X + xbase[band] + (size_t)o_local * bins * 16;
    const float inv = 1.0f / 3000.0f;
    for (int k = threadIdx.x; k < bins * 16; k += 256) {
        int f_local = k >> 4;
        float scale = ((start + f_local) == 0) ? inv : 2.0f * inv;
        XL[k] = xp[k] * scale;
    }
    __syncthreads();
    int t = blockIdx.y * 256 + threadIdx.x;
    if (t >= TOUT) return;

    // r = e^{-2pi i f t/3000} starting at f=start; w = e^{-2pi i t/3000}
    float ws_, wc_;
    int idx0 = (start * t) % 3000;
    __sincosf((float)idx0 * TWO_PI_OVER_L, &ws_, &wc_);
    float rr = wc_, ri = -ws_;
    __sincosf((float)t * TWO_PI_OVER_L, &ws_, &wc_);
    float wr = wc_, wi = -ws_;

    float acc[NB] = {0.f,0.f,0.f,0.f,0.f,0.f,0.f,0.f};
    #pragma unroll 2
    for (int fl = 0; fl < bins; ++fl) {
        const float4* xf = (const float4*)(XL + (fl << 4));
        float4 x0 = xf[0], x1 = xf[1], x2 = xf[2], x3 = xf[3];
        // acc_b += Xr*cos - Xi*sin = Xr*rr + Xi*ri   (ri = -sin)
        acc[0] = fmaf(x0.x, rr, acc[0]); acc[0] = fmaf(x0.y, ri, acc[0]);
        acc[1] = fmaf(x0.z, rr, acc[1]); acc[1] = fmaf(x0.w, ri, acc[1]);
        acc[2] = fmaf(x1.x, rr, acc[2]); acc[2] = fmaf(x1.y, ri, acc[2]);
        acc[3] = fmaf(x1.z, rr, acc[3]); acc[3] = fmaf(x1.w, ri, acc[3]);
        acc[4] = fmaf(x2.x, rr, acc[4]); acc[4] = fmaf(x2.y, ri, acc[4]);
        acc[5] = fmaf(x2.z, rr, acc[5]); acc[5] = fmaf(x2.w, ri, acc[5]);
        acc[6] = fmaf(x3.x, rr, acc[6]); acc[6] = fmaf(x3.y, ri, acc[6]);
        acc[7] = fmaf(x3.z, rr, acc[7]); acc[7] = fmaf(x3.w, ri, acc[7]);
        float nr = fmaf(-ri, wi, rr * wr);
        float ni = fmaf( ri, wr, rr * wi);
        rr = nr; ri = ni;
    }
    float bv = bias[o];
    #pragma unroll
    for (int b = 0; b < NB; ++b) {
        out[((size_t)b * COUT + o) * TOUT + t] = acc[b] + bv;
    }
}

extern "C" void kernel_launch(void* const* d_in, const int* in_sizes, int n_in,
                              void* d_out, int out_size, void* d_ws, size_t ws_size,
                              hipStream_t stream) {
    const float* sig  = (const float*)d_in[0];   // (8,64,3000) f32
    const float* w    = (const float*)d_in[1];   // (128,64,25) f32
    const float* bias = (const float*)d_in[2];   // (128,) f32
    float* out = (float*)d_out;
    float* ws  = (float*)d_ws;
    float* S  = ws + S_OFF;
    float* Wc = ws + WC_OFF;
    float* X  = ws + X_OFF;

    k_sig_dft<<<dim3(128, 4), 256, 0, stream>>>(sig, S);
    k_w_dft  <<<dim3(128, 2), 256, 0, stream>>>(w, Wc);
    k_mix    <<<dim3(809),    256, 0, stream>>>(S, Wc, X);
    k_idft   <<<dim3(128, 12),256, 0, stream>>>(X, bias, out);
}

// Round 3
// 213.415 us; speedup vs baseline: 2.4610x; 1.3213x over previous
//
#include <hip/hip_runtime.h>

#define L_SIG 3000
#define KPAD 3072           // K padded to 96*32
#define NB 8
#define CIN 64
#define COUT 128
#define KW 25
#define TOUT 2976
#define FMAXB 973           // frequency bins used: 0..972
#define NCOLS 1946          // 2*FMAXB (re,im interleaved as columns)
#define NPAD 1984           // 31*64

// ws byte layout (aliasing is stream-order-safe):
//  [0,        3145728)  A f16 [512][3072]      -> later X f32 (A dead after GEMM)
//  [3145728,  7131136)  S f32 [512][1946]
//  [7131136, 19320832)  B f16 [1984][3072]     -> later Wc f32 (B dead after GEMM)
#define A_BYTE   0
#define S_BYTE   3145728
#define B_BYTE   7131136
#define X_BYTE   0
#define WC_BYTE  7131136

typedef _Float16 f16x8 __attribute__((ext_vector_type(8)));
typedef float f32x4 __attribute__((ext_vector_type(4)));

typedef __attribute__((address_space(1))) const unsigned GU;
typedef __attribute__((address_space(3))) unsigned LU;
#define GL16(g, l) __builtin_amdgcn_global_load_lds((GU*)(g), (LU*)(l), 16, 0, 0)

#define TWO_PI_OVER_L 0.00209439510239319549f

// ---------------- gen A: signal f32 -> f16, pre-swizzled, K-padded ------
__global__ __launch_bounds__(256) void k_gen_a(const float* __restrict__ sig,
                                               _Float16* __restrict__ A) {
    int row = blockIdx.y;                    // 0..511
    int g = blockIdx.x * 256 + threadIdx.x;  // granule (8 halfs = 16B)
    if (g >= KPAD / 8) return;
    int gsw = (g & ~7) | ((g & 7) ^ (row & 7));   // T2 XOR swizzle in global
    union { _Float16 h[8]; uint4 u; } p;
    if (g < L_SIG / 8) {
        const float4* s4 = (const float4*)(sig + (size_t)row * L_SIG + g * 8);
        float4 a = s4[0], b = s4[1];
        p.h[0]=(_Float16)a.x; p.h[1]=(_Float16)a.y; p.h[2]=(_Float16)a.z; p.h[3]=(_Float16)a.w;
        p.h[4]=(_Float16)b.x; p.h[5]=(_Float16)b.y; p.h[6]=(_Float16)b.z; p.h[7]=(_Float16)b.w;
    } else {
        p.u = make_uint4(0, 0, 0, 0);        // K-pad zeros
    }
    ((uint4*)A)[(size_t)row * (KPAD / 8) + gsw] = p.u;
}

// ---------------- gen B: twiddle matrix f16, [n][k], pre-swizzled -------
// B[n=2f+c][k] = c==0 ? cos(2pi f k/L) : -sin(2pi f k/L); zeros in pads.
__global__ __launch_bounds__(256) void k_gen_b(_Float16* __restrict__ B) {
    int n = blockIdx.y;                      // 0..1983
    int g = blockIdx.x * 256 + threadIdx.x;
    if (g >= KPAD / 8) return;
    int f = n >> 1, c = n & 1;
    int gsw = (g & ~7) | ((g & 7) ^ (n & 7));
    union { _Float16 h[8]; uint4 u; } p;
    p.u = make_uint4(0, 0, 0, 0);
    if (f < FMAXB && g < L_SIG / 8) {
        int k0 = g * 8;
        int m0 = (int)(((long long)f * k0) % 3000);
        float s0, c0, sw, cw;
        __sincosf((float)m0 * TWO_PI_OVER_L, &s0, &c0);
        __sincosf((float)f * TWO_PI_OVER_L, &sw, &cw);
        float rr = c0, ri = -s0;             // e^{-i 2pi f k0 / L}
        #pragma unroll
        for (int j = 0; j < 8; ++j) {
            p.h[j] = (_Float16)(c ? ri : rr);
            float nr = rr * cw + ri * sw;    // r *= e^{-i 2pi f/L}
            float ni = ri * cw - rr * sw;
            rr = nr; ri = ni;
        }
    }
    ((uint4*)B)[(size_t)n * (KPAD / 8) + gsw] = p.u;
}

// ---------------- MFMA GEMM: S[512][1946] = A[512][3072] x B^T ----------
// 64x64 tile, BK=64, 4 waves (2x2), wave-tile 32x32, f16 16x16x32 MFMA.
__global__ __launch_bounds__(256) void k_dft_mm(const _Float16* __restrict__ A,
                                                const _Float16* __restrict__ B,
                                                float* __restrict__ S) {
    __shared__ _Float16 As[64 * 64];   // 8 KB, rows k-contiguous, swizzled
    __shared__ _Float16 Bs[64 * 64];   // 8 KB, [n][k]
    int row0 = blockIdx.y * 64;
    int col0 = blockIdx.x * 64;
    int tid = threadIdx.x;
    int wid = tid >> 6, lane = tid & 63;
    int wr = wid >> 1, wc = wid & 1;
    f32x4 acc[2][2] = {};

    for (int kt = 0; kt < KPAD / 64; ++kt) {
        int k0 = kt * 64;
        #pragma unroll
        for (int it = 0; it < 2; ++it) {
            int cb = it * 256 + wid * 64;         // wave-uniform chunk base
            int cA = cb + lane;                   // chunk = (row<<3)|cir
            int ar = cA >> 3, cir = cA & 7;
            const char* asrc = (const char*)A +
                ((size_t)(row0 + ar) * KPAD + k0) * 2 + cir * 16;
            GL16(asrc, (char*)As + cb * 16);
            const char* bsrc = (const char*)B +
                ((size_t)(col0 + ar) * KPAD + k0) * 2 + cir * 16;
            GL16(bsrc, (char*)Bs + cb * 16);
        }
        asm volatile("s_waitcnt vmcnt(0)" ::: "memory");
        __syncthreads();
        #pragma unroll
        for (int ks = 0; ks < 2; ++ks) {
            f16x8 av[2], bv[2];
            #pragma unroll
            for (int m = 0; m < 2; ++m) {
                int r = wr * 32 + m * 16 + (lane & 15);
                int g = (ks * 4 + (lane >> 4)) ^ (r & 7);
                av[m] = *(const f16x8*)(As + r * 64 + g * 8);
            }
            #pragma unroll
            for (int n = 0; n < 2; ++n) {
                int r = wc * 32 + n * 16 + (lane & 15);
                int g = (ks * 4 + (lane >> 4)) ^ (r & 7);
                bv[n] = *(const f16x8*)(Bs + r * 64 + g * 8);
            }
            #pragma unroll
            for (int m = 0; m < 2; ++m)
                #pragma unroll
                for (int n = 0; n < 2; ++n)
                    acc[m][n] = __builtin_amdgcn_mfma_f32_16x16x32_f16(
                        av[m], bv[n], acc[m][n], 0, 0, 0);
        }
        __syncthreads();
    }
    // epilogue: D col = lane&15, row = (lane>>4)*4 + j  [m89-verified]
    #pragma unroll
    for (int m = 0; m < 2; ++m)
        #pragma unroll
        for (int n = 0; n < 2; ++n) {
            int col = col0 + wc * 32 + n * 16 + (lane & 15);
            if (col < NCOLS) {
                int rowb = row0 + wr * 32 + m * 16 + (lane >> 4) * 4;
                #pragma unroll
                for (int j = 0; j < 4; ++j)
                    S[(size_t)(rowb + j) * NCOLS + col] = acc[m][n][j];
            }
        }
}

// ---------------- K2: weight DFT (conj) per band ------------------------
__global__ __launch_bounds__(256) void k_w_dft(const float* __restrict__ w,
                                               float* __restrict__ Wc) {
    __shared__ float wL[CIN * KW];
    const int startv[5] = {0,122,244,366,488};
    const int binsv[5]  = {123,123,123,123,485};
    const int n_ov[5]   = {25,25,25,25,28};
    const size_t wbase[5] = {0, 393600, 787200, 1180800, 1574400};
    int o = blockIdx.x;
    int band = min(o / 25, 4);
    int o_local = o - band * 25;
    int bins = binsv[band];
    int f = blockIdx.y * 256 + threadIdx.x;
    const float* wrow = w + (size_t)o * CIN * KW;
    for (int k = threadIdx.x; k < CIN * KW; k += 256) wL[k] = wrow[k];
    __syncthreads();
    if (f >= bins) return;
    int n_o = n_ov[band];
    int fg = startv[band] + f;
    float ws_, wc_;
    __sincosf((float)fg * TWO_PI_OVER_L, &ws_, &wc_);
    float wr = wc_, wi = ws_;    // conj roots: +sin
    float* outp = Wc + wbase[band] + (((size_t)f * n_o + o_local) * 64) * 2;
    for (int i = 0; i < CIN; ++i) {
        float ar = 0.f, ai = 0.f;
        float rr = 1.0f, ri = 0.0f;
        const float* wv = wL + i * KW;
        #pragma unroll
        for (int t = 0; t < KW; ++t) {
            float x = wv[t];
            ar = fmaf(x, rr, ar);
            ai = fmaf(x, ri, ai);
            float nr = fmaf(-ri, wi, rr * wr);
            float ni = fmaf( ri, wr, rr * wi);
            rr = nr; ri = ni;
        }
        outp[i * 2] = ar; outp[i * 2 + 1] = ai;
    }
}

// ---------------- K3: per-bin mix  X = sum_i S * Wc ---------------------
__global__ __launch_bounds__(256) void k_mix(const float* __restrict__ S,
                                             const float* __restrict__ Wc,
                                             float* __restrict__ X) {
    const int startv[5] = {0,122,244,366,488};
    const int binsv[5]  = {123,123,123,123,485};
    const int n_ov[5]   = {25,25,25,25,28};
    const size_t wbase[5] = {0, 393600, 787200, 1180800, 1574400};
    const size_t xbase[5] = {0, 49200, 98400, 147600, 196800};
    const int cum[6] = {0, 24600, 49200, 73800, 98400, 207040};
    int gid = blockIdx.x * 256 + threadIdx.x;
    if (gid >= 207040) return;
    int band = 0;
    while (gid >= cum[band + 1]) band++;
    int r = gid - cum[band];
    int b = r & 7;
    int t2 = r >> 3;
    int bins = binsv[band];
    int f_local = t2 % bins;
    int o_local = t2 / bins;
    int n_o = n_ov[band];
    int fg = startv[band] + f_local;
    const float* sp = S + (((size_t)b * 64) * FMAXB + fg) * 2;
    const float* wp = Wc + wbase[band] + (((size_t)f_local * n_o + o_local) * 64) * 2;
    float xr = 0.f, xi = 0.f;
    #pragma unroll 8
    for (int i = 0; i < CIN; ++i) {
        float sr = sp[i * 2 * FMAXB], si = sp[i * 2 * FMAXB + 1];
        float wr = wp[i * 2], wi = wp[i * 2 + 1];
        xr = fmaf(sr, wr, xr); xr = fmaf(-si, wi, xr);
        xi = fmaf(sr, wi, xi); xi = fmaf(si, wr, xi);
    }
    float* xp = X + xbase[band] + (((size_t)o_local * bins + f_local) * 8 + b) * 2;
    xp[0] = xr; xp[1] = xi;
}

// ---------------- K4: inverse DFT (band-limited) + bias -----------------
__global__ __launch_bounds__(256) void k_idft(const float* __restrict__ X,
                                              const float* __restrict__ bias,
                                              float* __restrict__ out) {
    __shared__ float XL[485 * 16];   // [f_local][b][2], pre-scaled
    const int startv[5] = {0,122,244,366,488};
    const int binsv[5]  = {123,123,123,123,485};
    const size_t xbase[5] = {0, 49200, 98400, 147600, 196800};
    int o = blockIdx.x;
    int band = min(o / 25, 4);
    int o_local = o - band * 25;
    int bins = binsv[band];
    int start = startv[band];
    const float* xp = X + xbase[band] + (size_t)o_local * bins * 16;
    const float inv = 1.0f / 3000.0f;
    for (int k = threadIdx.x; k < bins * 16; k += 256) {
        int f_local = k >> 4;
        float scale = ((start + f_local) == 0) ? inv : 2.0f * inv;
        XL[k] = xp[k] * scale;
    }
    __syncthreads();
    int t = blockIdx.y * 256 + threadIdx.x;
    if (t >= TOUT) return;

    float ws_, wc_;
    int idx0 = (start * t) % 3000;
    __sincosf((float)idx0 * TWO_PI_OVER_L, &ws_, &wc_);
    float rr = wc_, ri = -ws_;
    __sincosf((float)t * TWO_PI_OVER_L, &ws_, &wc_);
    float wr = wc_, wi = -ws_;

    float acc[NB] = {0.f,0.f,0.f,0.f,0.f,0.f,0.f,0.f};
    #pragma unroll 2
    for (int fl = 0; fl < bins; ++fl) {
        const float4* xf = (const float4*)(XL + (fl << 4));
        float4 x0 = xf[0], x1 = xf[1], x2 = xf[2], x3 = xf[3];
        acc[0] = fmaf(x0.x, rr, acc[0]); acc[0] = fmaf(x0.y, ri, acc[0]);
        acc[1] = fmaf(x0.z, rr, acc[1]); acc[1] = fmaf(x0.w, ri, acc[1]);
        acc[2] = fmaf(x1.x, rr, acc[2]); acc[2] = fmaf(x1.y, ri, acc[2]);
        acc[3] = fmaf(x1.z, rr, acc[3]); acc[3] = fmaf(x1.w, ri, acc[3]);
        acc[4] = fmaf(x2.x, rr, acc[4]); acc[4] = fmaf(x2.y, ri, acc[4]);
        acc[5] = fmaf(x2.z, rr, acc[5]); acc[5] = fmaf(x2.w, ri, acc[5]);
        acc[6] = fmaf(x3.x, rr, acc[6]); acc[6] = fmaf(x3.y, ri, acc[6]);
        acc[7] = fmaf(x3.z, rr, acc[7]); acc[7] = fmaf(x3.w, ri, acc[7]);
        float nr = fmaf(-ri, wi, rr * wr);
        float ni = fmaf( ri, wr, rr * wi);
        rr = nr; ri = ni;
    }
    float bv = bias[o];
    #pragma unroll
    for (int b = 0; b < NB; ++b) {
        out[((size_t)b * COUT + o) * TOUT + t] = acc[b] + bv;
    }
}

extern "C" void kernel_launch(void* const* d_in, const int* in_sizes, int n_in,
                              void* d_out, int out_size, void* d_ws, size_t ws_size,
                              hipStream_t stream) {
    const float* sig  = (const float*)d_in[0];   // (8,64,3000) f32
    const float* w    = (const float*)d_in[1];   // (128,64,25) f32
    const float* bias = (const float*)d_in[2];   // (128,) f32
    float* out = (float*)d_out;
    char* wsb = (char*)d_ws;
    _Float16* A = (_Float16*)(wsb + A_BYTE);
    float*    S = (float*)(wsb + S_BYTE);
    _Float16* B = (_Float16*)(wsb + B_BYTE);
    float*    Wc = (float*)(wsb + WC_BYTE);   // aliases B (dead after GEMM)
    float*    X  = (float*)(wsb + X_BYTE);    // aliases A (dead after GEMM)

    k_gen_a <<<dim3(2, 512),  256, 0, stream>>>(sig, A);
    k_gen_b <<<dim3(2, NPAD), 256, 0, stream>>>(B);
    k_dft_mm<<<dim3(31, 8),   256, 0, stream>>>(A, B, S);
    k_w_dft <<<dim3(128, 2),  256, 0, stream>>>(w, Wc);
    k_mix   <<<dim3(809),     256, 0, stream>>>(S, Wc, X);
    k_idft  <<<dim3(128, 12), 256, 0, stream>>>(X, bias, out);
}

// Round 5
// 116.873 us; speedup vs baseline: 4.4938x; 1.8260x over previous
//
#include <hip/hip_runtime.h>

#define L_SIG 3000
#define KPAD 3008           // 47*64
#define NB 8
#define CIN 64
#define COUT 128
#define KW 25
#define TOUT 2976
#define FMAXB 973
#define NCOLS 1946          // 2*FMAXB
#define NPAD 1984           // 31*64
#define TSTRIDE 2000        // T cols (halfs), multiple of 8
#define TROWS 3008          // 47*64

// ws byte layout (15,073,280 B total; <= 18.4 MB proven-safe):
//  [0, 12032000)          T_idft f16 [3008][2000]   (A_fwd f16 [512][3008] =
//                         3,080,192 B aliases the front during the fwd phase)
//  [12032000, 14024704)   S16 f16 [512][1946]       (1,992,704 B)
//  [14024704, 15073280)   A_idft f16 (524,288 halfs = 1,048,576 B)
// d_out (12,189,696 B) is used as scratch, stream-ordered:
//   phase 1: B_fwd f16 [1984][3008] (11,935,744 B)   dead after k_dft_mm
//   phase 2: Wc f16 (3,312,640 halfs = 6,625,280 B)  dead after k_mix
//   phase 3: final output (every element overwritten by k_idft_mm)
#define T_BYTE     0
#define A_FWD_BYTE 0
#define S_BYTE     12032000
#define AID_BYTE   14024704

typedef _Float16 f16x8 __attribute__((ext_vector_type(8)));
typedef float f32x4 __attribute__((ext_vector_type(4)));

typedef __attribute__((address_space(1))) const unsigned GU;
typedef __attribute__((address_space(3))) unsigned LU;
#define GL16(g, l) __builtin_amdgcn_global_load_lds((GU*)(g), (LU*)(l), 16, 0, 0)

#define TWO_PI_OVER_L 0.00209439510239319549f

__device__ __forceinline__ float2 h2f2(unsigned u) {
    union { unsigned u; _Float16 h[2]; } p; p.u = u;
    return make_float2((float)p.h[0], (float)p.h[1]);
}
__device__ __forceinline__ unsigned f2h2(float a, float b) {
    union { unsigned u; _Float16 h[2]; } p;
    p.h[0] = (_Float16)a; p.h[1] = (_Float16)b; return p.u;
}

// ---------------- gen A_fwd: signal f32 -> f16, pre-swizzled ------------
__global__ __launch_bounds__(256) void k_gen_a(const float* __restrict__ sig,
                                               _Float16* __restrict__ A) {
    int row = blockIdx.y;                    // 0..511
    int g = blockIdx.x * 256 + threadIdx.x;  // granule (8 halfs = 16B)
    if (g >= KPAD / 8) return;
    int gsw = (g & ~7) | ((g & 7) ^ (row & 7));
    union { _Float16 h[8]; uint4 u; } p;
    if (g < L_SIG / 8) {
        const float4* s4 = (const float4*)(sig + (size_t)row * L_SIG + g * 8);
        float4 a = s4[0], b = s4[1];
        p.h[0]=(_Float16)a.x; p.h[1]=(_Float16)a.y; p.h[2]=(_Float16)a.z; p.h[3]=(_Float16)a.w;
        p.h[4]=(_Float16)b.x; p.h[5]=(_Float16)b.y; p.h[6]=(_Float16)b.z; p.h[7]=(_Float16)b.w;
    } else {
        p.u = make_uint4(0, 0, 0, 0);
    }
    ((uint4*)A)[(size_t)row * (KPAD / 8) + gsw] = p.u;
}

// ---------------- gen B_fwd: fwd twiddles f16 [n][k], pre-swizzled ------
__global__ __launch_bounds__(256) void k_gen_b(_Float16* __restrict__ B) {
    int n = blockIdx.y;                      // 0..1983
    int g = blockIdx.x * 256 + threadIdx.x;
    if (g >= KPAD / 8) return;
    int f = n >> 1, c = n & 1;
    int gsw = (g & ~7) | ((g & 7) ^ (n & 7));
    union { _Float16 h[8]; uint4 u; } p;
    p.u = make_uint4(0, 0, 0, 0);
    if (f < FMAXB && g < L_SIG / 8) {
        int k0 = g * 8;
        int m0 = (int)(((long long)f * k0) % 3000);
        float s0, c0, sw, cw;
        __sincosf((float)m0 * TWO_PI_OVER_L, &s0, &c0);
        __sincosf((float)f * TWO_PI_OVER_L, &sw, &cw);
        float rr = c0, ri = -s0;             // e^{-i 2pi f k0 / L}
        #pragma unroll
        for (int j = 0; j < 8; ++j) {
            p.h[j] = (_Float16)(c ? ri : rr);
            float nr = rr * cw + ri * sw;
            float ni = ri * cw - rr * sw;
            rr = nr; ri = ni;
        }
    }
    ((uint4*)B)[(size_t)n * (KPAD / 8) + gsw] = p.u;
}

// ---------------- fwd MFMA GEMM: S16[512][1946] = A x B^T ---------------
__global__ __launch_bounds__(256) void k_dft_mm(const _Float16* __restrict__ A,
                                                const _Float16* __restrict__ B,
                                                _Float16* __restrict__ S16) {
    __shared__ _Float16 As[64 * 64];
    __shared__ _Float16 Bs[64 * 64];
    int row0 = blockIdx.y * 64;
    int col0 = blockIdx.x * 64;
    int tid = threadIdx.x;
    int wid = tid >> 6, lane = tid & 63;
    int wr = wid >> 1, wc = wid & 1;
    f32x4 acc[2][2] = {};

    for (int kt = 0; kt < KPAD / 64; ++kt) {
        int k0 = kt * 64;
        #pragma unroll
        for (int it = 0; it < 2; ++it) {
            int cb = it * 256 + wid * 64;
            int cA = cb + lane;
            int ar = cA >> 3, cir = cA & 7;
            const char* asrc = (const char*)A +
                ((size_t)(row0 + ar) * KPAD + k0) * 2 + cir * 16;
            GL16(asrc, (char*)As + cb * 16);
            const char* bsrc = (const char*)B +
                ((size_t)(col0 + ar) * KPAD + k0) * 2 + cir * 16;
            GL16(bsrc, (char*)Bs + cb * 16);
        }
        asm volatile("s_waitcnt vmcnt(0)" ::: "memory");
        __syncthreads();
        #pragma unroll
        for (int ks = 0; ks < 2; ++ks) {
            f16x8 av[2], bv[2];
            #pragma unroll
            for (int m = 0; m < 2; ++m) {
                int r = wr * 32 + m * 16 + (lane & 15);
                int g = (ks * 4 + (lane >> 4)) ^ (r & 7);
                av[m] = *(const f16x8*)(As + r * 64 + g * 8);
            }
            #pragma unroll
            for (int n = 0; n < 2; ++n) {
                int r = wc * 32 + n * 16 + (lane & 15);
                int g = (ks * 4 + (lane >> 4)) ^ (r & 7);
                bv[n] = *(const f16x8*)(Bs + r * 64 + g * 8);
            }
            #pragma unroll
            for (int m = 0; m < 2; ++m)
                #pragma unroll
                for (int n = 0; n < 2; ++n)
                    acc[m][n] = __builtin_amdgcn_mfma_f32_16x16x32_f16(
                        av[m], bv[n], acc[m][n], 0, 0, 0);
        }
        __syncthreads();
    }
    #pragma unroll
    for (int m = 0; m < 2; ++m)
        #pragma unroll
        for (int n = 0; n < 2; ++n) {
            int col = col0 + wc * 32 + n * 16 + (lane & 15);
            if (col < NCOLS) {
                int rowb = row0 + wr * 32 + m * 16 + (lane >> 4) * 4;
                #pragma unroll
                for (int j = 0; j < 4; ++j)
                    S16[(size_t)(rowb + j) * NCOLS + col] = (_Float16)acc[m][n][j];
            }
        }
}

// ---------------- weight DFT (conj) per band, f16 out (into d_out) ------
__global__ __launch_bounds__(256) void k_w_dft(const float* __restrict__ w,
                                               _Float16* __restrict__ Wc) {
    __shared__ float wL[CIN * KW];
    const int startv[5] = {0,122,244,366,488};
    const int binsv[5]  = {123,123,123,123,485};
    const int n_ov[5]   = {25,25,25,25,28};
    const size_t wbase[5] = {0, 393600, 787200, 1180800, 1574400};  // halfs
    int o = blockIdx.x;
    int band = min(o / 25, 4);
    int o_local = o - band * 25;
    int bins = binsv[band];
    int f = blockIdx.y * 256 + threadIdx.x;
    const float* wrow = w + (size_t)o * CIN * KW;
    for (int k = threadIdx.x; k < CIN * KW; k += 256) wL[k] = wrow[k];
    __syncthreads();
    if (f >= bins) return;
    int n_o = n_ov[band];
    int fg = startv[band] + f;
    float ws_, wc_;
    __sincosf((float)fg * TWO_PI_OVER_L, &ws_, &wc_);
    float wr = wc_, wi = ws_;    // conj roots: +sin
    unsigned* outp = (unsigned*)Wc + (wbase[band] >> 1) + ((size_t)f * n_o + o_local) * 64;
    for (int i = 0; i < CIN; ++i) {
        float ar = 0.f, ai = 0.f;
        float rr = 1.0f, ri = 0.0f;
        const float* wv = wL + i * KW;
        #pragma unroll
        for (int t = 0; t < KW; ++t) {
            float x = wv[t];
            ar = fmaf(x, rr, ar);
            ai = fmaf(x, ri, ai);
            float nr = fmaf(-ri, wi, rr * wr);
            float ni = fmaf( ri, wr, rr * wi);
            rr = nr; ri = ni;
        }
        outp[i] = f2h2(ar, ai);
    }
}

// ---------------- gen T_idft: f16 [t][n], LINEAR ------------------------
// T[t][n] = (n even ? cos : -sin)(2pi*(n>>1)*t/L); zero for n >= 1946.
__global__ __launch_bounds__(256) void k_gen_t(_Float16* __restrict__ T) {
    int t = blockIdx.x;
    int g = threadIdx.x;                     // granule: 8 n's
    if (g >= TSTRIDE / 8) return;
    union { _Float16 h[8]; uint4 u; } p;
    p.u = make_uint4(0, 0, 0, 0);
    int f0 = g * 4;                          // n = 8g.. -> f = 4g..4g+3
    if (f0 < FMAXB) {
        int m0 = (int)(((long long)f0 * t) % 3000);
        float s0, c0, sw, cw;
        __sincosf((float)m0 * TWO_PI_OVER_L, &s0, &c0);
        __sincosf((float)t * TWO_PI_OVER_L, &sw, &cw);
        float rr = c0, ri = -s0;             // (cos, -sin) at f0
        #pragma unroll
        for (int j = 0; j < 4; ++j) {
            if (f0 + j < FMAXB) {
                p.h[2 * j]     = (_Float16)rr;
                p.h[2 * j + 1] = (_Float16)ri;
            }
            float nr = rr * cw + ri * sw;    // rotate by e^{-i 2pi t/L}
            float ni = ri * cw - rr * sw;
            rr = nr; ri = ni;
        }
    }
    ((uint4*)T)[(size_t)t * (TSTRIDE / 8) + g] = p.u;
}

// ---------------- zero A_idft -------------------------------------------
__global__ __launch_bounds__(256) void k_zero(uint4* __restrict__ p) {
    p[blockIdx.x * 256 + threadIdx.x] = make_uint4(0, 0, 0, 0);  // 65536 uint4
}

// ---------------- mix: A_idft[(band,o,b)][k] = scale * sum_i S*Wc -------
__global__ __launch_bounds__(256) void k_mix(const _Float16* __restrict__ S16,
                                             const _Float16* __restrict__ Wc,
                                             _Float16* __restrict__ Aid) {
    const int startv[5] = {0,122,244,366,488};
    const int binsv[5]  = {123,123,123,123,485};
    const int n_ov[5]   = {25,25,25,25,28};
    const int dltv[5]   = {0,4,0,4,0};
    const int khv[5]    = {256,256,256,256,1024};
    const size_t wbase[5] = {0, 393600, 787200, 1180800, 1574400};  // halfs
    const size_t abase[5] = {0, 65536, 131072, 196608, 262144};     // halfs
    const int cum[6] = {0, 24600, 49200, 73800, 98400, 207040};
    int gid = blockIdx.x * 256 + threadIdx.x;
    if (gid >= 207040) return;
    int band = 0;
    while (gid >= cum[band + 1]) band++;
    int r = gid - cum[band];
    int b = r & 7;
    int t2 = r >> 3;
    int bins = binsv[band];
    int f_local = t2 % bins;
    int o_local = t2 / bins;
    int n_o = n_ov[band];
    int fg = startv[band] + f_local;
    const unsigned* sp = (const unsigned*)S16 + (size_t)(b * 64) * (NCOLS / 2) + fg;
    const unsigned* wp = (const unsigned*)Wc + (wbase[band] >> 1) + ((size_t)f_local * n_o + o_local) * 64;
    float xr = 0.f, xi = 0.f;
    #pragma unroll 8
    for (int i = 0; i < CIN; ++i) {
        float2 s = h2f2(sp[(size_t)i * (NCOLS / 2)]);
        float2 wv = h2f2(wp[i]);
        xr = fmaf(s.x, wv.x, xr); xr = fmaf(-s.y, wv.y, xr);
        xi = fmaf(s.x, wv.y, xi); xi = fmaf(s.y, wv.x, xi);
    }
    float scale = (fg == 0 ? 1.0f : 2.0f) / 3000.0f;
    size_t hoff = abase[band] + (size_t)(o_local * 8 + b) * khv[band] + 2 * f_local + dltv[band];
    ((unsigned*)Aid)[hoff >> 1] = f2h2(xr * scale, xi * scale);
}

// ---------------- idft MFMA GEMM + bias ---------------------------------
// out[(b,o)][t] = bias[o] + A_idft[bandrow][k] . T[t][n0+k]
__global__ __launch_bounds__(256) void k_idft_mm(const _Float16* __restrict__ Aid,
                                                 const _Float16* __restrict__ T,
                                                 const float* __restrict__ bias,
                                                 float* __restrict__ out) {
    __shared__ _Float16 As[64 * 64];
    __shared__ _Float16 Bs[64 * 64];
    const int n0v[5] = {0, 240, 488, 728, 976};
    const int n_ov[5] = {25,25,25,25,28};
    const size_t abase[5] = {0, 65536, 131072, 196608, 262144};
    int mt = blockIdx.y;                 // 0..19
    int band = mt >> 2;
    int row0b = (mt & 3) * 64;           // row within band (256-padded)
    int col0 = blockIdx.x * 64;          // t tile
    int Kh = (band < 4) ? 256 : 1024;
    int nkt = Kh / 64;
    const char* Ab = (const char*)Aid + abase[band] * 2;
    const char* Bb = (const char*)T + (size_t)n0v[band] * 2;
    int tid = threadIdx.x;
    int wid = tid >> 6, lane = tid & 63;
    int wr = wid >> 1, wc = wid & 1;
    f32x4 acc[2][2] = {};

    for (int kt = 0; kt < nkt; ++kt) {
        int k0 = kt * 64;
        #pragma unroll
        for (int it = 0; it < 2; ++it) {
            int cb = it * 256 + wid * 64;
            int cA = cb + lane;
            int ar = cA >> 3, cir = cA & 7;
            int cirs = cir ^ (ar & 7);              // swizzle in SOURCE addr
            const char* asrc = Ab + ((size_t)(row0b + ar) * Kh + k0) * 2 + cirs * 16;
            GL16(asrc, (char*)As + cb * 16);
            const char* bsrc = Bb + ((size_t)(col0 + ar) * TSTRIDE + k0) * 2 + cirs * 16;
            GL16(bsrc, (char*)Bs + cb * 16);
        }
        asm volatile("s_waitcnt vmcnt(0)" ::: "memory");
        __syncthreads();
        #pragma unroll
        for (int ks = 0; ks < 2; ++ks) {
            f16x8 av[2], bv[2];
            #pragma unroll
            for (int m = 0; m < 2; ++m) {
                int r = wr * 32 + m * 16 + (lane & 15);
                int g = (ks * 4 + (lane >> 4)) ^ (r & 7);
                av[m] = *(const f16x8*)(As + r * 64 + g * 8);
            }
            #pragma unroll
            for (int n = 0; n < 2; ++n) {
                int r = wc * 32 + n * 16 + (lane & 15);
                int g = (ks * 4 + (lane >> 4)) ^ (r & 7);
                bv[n] = *(const f16x8*)(Bs + r * 64 + g * 8);
            }
            #pragma unroll
            for (int m = 0; m < 2; ++m)
                #pragma unroll
                for (int n = 0; n < 2; ++n)
                    acc[m][n] = __builtin_amdgcn_mfma_f32_16x16x32_f16(
                        av[m], bv[n], acc[m][n], 0, 0, 0);
        }
        __syncthreads();
    }
    int n_o8 = n_ov[band] * 8;
    #pragma unroll
    for (int m = 0; m < 2; ++m)
        #pragma unroll
        for (int n = 0; n < 2; ++n) {
            int t = col0 + wc * 32 + n * 16 + (lane & 15);
            if (t >= TOUT) continue;
            int rowb = row0b + wr * 32 + m * 16 + (lane >> 4) * 4;
            #pragma unroll
            for (int j = 0; j < 4; ++j) {
                int prb = rowb + j;
                if (prb < n_o8) {
                    int o = band * 25 + (prb >> 3);
                    int b = prb & 7;
                    out[((size_t)b * COUT + o) * TOUT + t] = acc[m][n][j] + bias[o];
                }
            }
        }
}

extern "C" void kernel_launch(void* const* d_in, const int* in_sizes, int n_in,
                              void* d_out, int out_size, void* d_ws, size_t ws_size,
                              hipStream_t stream) {
    const float* sig  = (const float*)d_in[0];   // (8,64,3000) f32
    const float* w    = (const float*)d_in[1];   // (128,64,25) f32
    const float* bias = (const float*)d_in[2];   // (128,) f32
    float* out = (float*)d_out;
    char* wsb = (char*)d_ws;
    _Float16* A_fwd = (_Float16*)(wsb + A_FWD_BYTE);
    _Float16* T     = (_Float16*)(wsb + T_BYTE);     // overwrites A_fwd later
    _Float16* S16   = (_Float16*)(wsb + S_BYTE);
    _Float16* Aid   = (_Float16*)(wsb + AID_BYTE);
    _Float16* B_fwd = (_Float16*)d_out;              // d_out scratch, phase 1
    _Float16* Wc    = (_Float16*)d_out;              // d_out scratch, phase 2

    k_gen_a  <<<dim3(2, 512),  256, 0, stream>>>(sig, A_fwd);
    k_gen_b  <<<dim3(2, NPAD), 256, 0, stream>>>(B_fwd);
    k_dft_mm <<<dim3(31, 8),   256, 0, stream>>>(A_fwd, B_fwd, S16);
    k_gen_t  <<<dim3(TROWS),   256, 0, stream>>>(T);      // after dft_mm (aliases A_fwd)
    k_w_dft  <<<dim3(128, 2),  256, 0, stream>>>(w, Wc);  // after dft_mm (aliases B_fwd)
    k_zero   <<<dim3(256),     256, 0, stream>>>((uint4*)Aid);
    k_mix    <<<dim3(809),     256, 0, stream>>>(S16, Wc, Aid);
    k_idft_mm<<<dim3(47, 20),  256, 0, stream>>>(Aid, T, bias, out);
}

// Round 6
// 116.063 us; speedup vs baseline: 4.5252x; 1.0070x over previous
//
#include <hip/hip_runtime.h>

#define L_SIG 3000
#define KPAD 3008           // 47*64
#define NB 8
#define CIN 64
#define COUT 128
#define KW 25
#define TOUT 2976
#define FMAXB 973
#define NCOLS 1946          // 2*FMAXB
#define NPAD 1984           // 31*64
#define TSTRIDE 2000        // T cols (halfs)
#define TROWS 3008          // 47*64

// ws byte layout (~45 MB of ~268 MB; NO aliasing):
//  [0,        3080192)   A_fwd f16 [512][3008], pre-swizzled
//  [3145728, 15081472)   B_fwd f16 [1984][3008], pre-swizzled
//  [15728640,27760640)   T_idft f16 [3008][2000], linear
//  [28311552,34936832)   Wc f16 (3,312,640 halfs = 6,625,280 B)
//  [35651584,43778048)   S_part f32 [2][1984][512]
//  [44040192,45088768)   A_idft f16 (524,288 halfs)
#define A_BYTE    0
#define B_BYTE    3145728
#define T_BYTE    15728640
#define WC_BYTE   28311552
#define SP_BYTE   35651584
#define AID_BYTE  44040192

typedef _Float16 f16x8 __attribute__((ext_vector_type(8)));
typedef float f32x4 __attribute__((ext_vector_type(4)));

typedef __attribute__((address_space(1))) const unsigned GU;
typedef __attribute__((address_space(3))) unsigned LU;
#define GL16(g, l) __builtin_amdgcn_global_load_lds((GU*)(g), (LU*)(l), 16, 0, 0)

#define TWO_PI_OVER_L 0.00209439510239319549f

__device__ __forceinline__ float2 h2f2(unsigned u) {
    union { unsigned u; _Float16 h[2]; } p; p.u = u;
    return make_float2((float)p.h[0], (float)p.h[1]);
}
__device__ __forceinline__ unsigned f2h2(float a, float b) {
    union { unsigned u; _Float16 h[2]; } p;
    p.h[0] = (_Float16)a; p.h[1] = (_Float16)b; return p.u;
}

// ================= fused prep: gen_a | gen_b | gen_t | w_dft | zero =====
// blocks: [0,1024) gen_a  [1024,4992) gen_b  [4992,8000) gen_t
//         [8000,8256) w_dft  [8256,8512) zero Aid
__global__ __launch_bounds__(256) void k_prep(const float* __restrict__ sig,
                                              const float* __restrict__ w,
                                              char* __restrict__ wsb) {
    __shared__ float wL[CIN * KW];
    int blk = blockIdx.x, tid = threadIdx.x;

    if (blk < 1024) {                        // ---- gen A_fwd (swizzled)
        _Float16* A = (_Float16*)(wsb + A_BYTE);
        int row = blk >> 1;
        int g = (blk & 1) * 256 + tid;
        if (g >= KPAD / 8) return;
        int gsw = (g & ~7) | ((g & 7) ^ (row & 7));
        union { _Float16 h[8]; uint4 u; } p;
        if (g < L_SIG / 8) {
            const float4* s4 = (const float4*)(sig + (size_t)row * L_SIG + g * 8);
            float4 a = s4[0], b = s4[1];
            p.h[0]=(_Float16)a.x; p.h[1]=(_Float16)a.y; p.h[2]=(_Float16)a.z; p.h[3]=(_Float16)a.w;
            p.h[4]=(_Float16)b.x; p.h[5]=(_Float16)b.y; p.h[6]=(_Float16)b.z; p.h[7]=(_Float16)b.w;
        } else p.u = make_uint4(0, 0, 0, 0);
        ((uint4*)A)[(size_t)row * (KPAD / 8) + gsw] = p.u;

    } else if (blk < 4992) {                 // ---- gen B_fwd (swizzled)
        _Float16* B = (_Float16*)(wsb + B_BYTE);
        int q = blk - 1024;
        int n = q >> 1;
        int g = (q & 1) * 256 + tid;
        if (g >= KPAD / 8) return;
        int f = n >> 1, c = n & 1;
        int gsw = (g & ~7) | ((g & 7) ^ (n & 7));
        union { _Float16 h[8]; uint4 u; } p;
        p.u = make_uint4(0, 0, 0, 0);
        if (f < FMAXB && g < L_SIG / 8) {
            int k0 = g * 8;
            int m0 = (int)(((long long)f * k0) % 3000);
            float s0, c0, sw, cw;
            __sincosf((float)m0 * TWO_PI_OVER_L, &s0, &c0);
            __sincosf((float)f * TWO_PI_OVER_L, &sw, &cw);
            float rr = c0, ri = -s0;         // e^{-i 2pi f k0/L}
            #pragma unroll
            for (int j = 0; j < 8; ++j) {
                p.h[j] = (_Float16)(c ? ri : rr);
                float nr = rr * cw + ri * sw;
                float ni = ri * cw - rr * sw;
                rr = nr; ri = ni;
            }
        }
        ((uint4*)B)[(size_t)n * (KPAD / 8) + gsw] = p.u;

    } else if (blk < 8000) {                 // ---- gen T_idft (linear)
        _Float16* T = (_Float16*)(wsb + T_BYTE);
        int t = blk - 4992;
        int g = tid;
        if (g >= TSTRIDE / 8) return;
        union { _Float16 h[8]; uint4 u; } p;
        p.u = make_uint4(0, 0, 0, 0);
        int f0 = g * 4;
        if (f0 < FMAXB) {
            int m0 = (int)(((long long)f0 * t) % 3000);
            float s0, c0, sw, cw;
            __sincosf((float)m0 * TWO_PI_OVER_L, &s0, &c0);
            __sincosf((float)t * TWO_PI_OVER_L, &sw, &cw);
            float rr = c0, ri = -s0;         // (cos, -sin) at f0
            #pragma unroll
            for (int j = 0; j < 4; ++j) {
                if (f0 + j < FMAXB) {
                    p.h[2 * j]     = (_Float16)rr;
                    p.h[2 * j + 1] = (_Float16)ri;
                }
                float nr = rr * cw + ri * sw;
                float ni = ri * cw - rr * sw;
                rr = nr; ri = ni;
            }
        }
        ((uint4*)T)[(size_t)t * (TSTRIDE / 8) + g] = p.u;

    } else if (blk < 8256) {                 // ---- weight DFT (conj)
        _Float16* Wc = (_Float16*)(wsb + WC_BYTE);
        const int startv[5] = {0,122,244,366,488};
        const int binsv[5]  = {123,123,123,123,485};
        const int n_ov[5]   = {25,25,25,25,28};
        const size_t wbase[5] = {0, 393600, 787200, 1180800, 1574400};  // halfs
        int q = blk - 8000;
        int o = q >> 1;
        int f = (q & 1) * 256 + tid;
        int band = min(o / 25, 4);
        int o_local = o - band * 25;
        int bins = binsv[band];
        const float* wrow = w + (size_t)o * CIN * KW;
        for (int k = tid; k < CIN * KW; k += 256) wL[k] = wrow[k];
        __syncthreads();
        if (f >= bins) return;
        int n_o = n_ov[band];
        int fg = startv[band] + f;
        float ws_, wc_;
        __sincosf((float)fg * TWO_PI_OVER_L, &ws_, &wc_);
        float wr = wc_, wi = ws_;            // conj roots: +sin
        unsigned* outp = (unsigned*)Wc + (wbase[band] >> 1) + ((size_t)f * n_o + o_local) * 64;
        for (int i = 0; i < CIN; ++i) {
            float ar = 0.f, ai = 0.f;
            float rr = 1.0f, ri = 0.0f;
            const float* wv = wL + i * KW;
            #pragma unroll
            for (int t = 0; t < KW; ++t) {
                float x = wv[t];
                ar = fmaf(x, rr, ar);
                ai = fmaf(x, ri, ai);
                float nr = fmaf(-ri, wi, rr * wr);
                float ni = fmaf( ri, wr, rr * wi);
                rr = nr; ri = ni;
            }
            outp[i] = f2h2(ar, ai);
        }

    } else {                                 // ---- zero A_idft
        uint4* Az = (uint4*)(wsb + AID_BYTE);
        int q = blk - 8256;
        Az[(size_t)q * 256 + tid] = make_uint4(0, 0, 0, 0);   // 65536 uint4
    }
}

// ================ fwd MFMA GEMM (split-K x2, dbuf): S_T = (A x B^T)^T ===
// grid (31, 16): y&7 = Mtile, y>>3 = K half. Output f32 [kh][n][512].
__global__ __launch_bounds__(256) void k_dft_mm(const _Float16* __restrict__ A,
                                                const _Float16* __restrict__ B,
                                                float* __restrict__ Sp) {
    __shared__ _Float16 As[2][64 * 64];
    __shared__ _Float16 Bs[2][64 * 64];
    int row0 = (blockIdx.y & 7) * 64;
    int kh   = blockIdx.y >> 3;
    int col0 = blockIdx.x * 64;
    int kt0  = kh ? 24 : 0;
    int nkt  = kh ? 23 : 24;
    int tid = threadIdx.x, wid = tid >> 6, lane = tid & 63;
    int wr = wid >> 1, wc = wid & 1;
    f32x4 acc[2][2] = {};

    auto stage = [&](int kt, int buf) {
        int k0 = (kt0 + kt) * 64;
        #pragma unroll
        for (int it = 0; it < 2; ++it) {
            int cb = it * 256 + wid * 64;
            int cA = cb + lane;
            int ar = cA >> 3, cir = cA & 7;
            GL16((const char*)A + ((size_t)(row0 + ar) * KPAD + k0) * 2 + cir * 16,
                 (char*)As[buf] + cb * 16);
            GL16((const char*)B + ((size_t)(col0 + ar) * KPAD + k0) * 2 + cir * 16,
                 (char*)Bs[buf] + cb * 16);
        }
    };
    stage(0, 0);
    for (int kt = 0; kt < nkt; ++kt) {
        int cur = kt & 1;
        asm volatile("s_waitcnt vmcnt(0)" ::: "memory");
        __syncthreads();
        if (kt + 1 < nkt) stage(kt + 1, cur ^ 1);
        #pragma unroll
        for (int ks = 0; ks < 2; ++ks) {
            f16x8 av[2], bv[2];
            #pragma unroll
            for (int m = 0; m < 2; ++m) {
                int r = wr * 32 + m * 16 + (lane & 15);
                int g = (ks * 4 + (lane >> 4)) ^ (r & 7);
                av[m] = *(const f16x8*)(As[cur] + r * 64 + g * 8);
            }
            #pragma unroll
            for (int n = 0; n < 2; ++n) {
                int r = wc * 32 + n * 16 + (lane & 15);
                int g = (ks * 4 + (lane >> 4)) ^ (r & 7);
                bv[n] = *(const f16x8*)(Bs[cur] + r * 64 + g * 8);
            }
            #pragma unroll
            for (int m = 0; m < 2; ++m)
                #pragma unroll
                for (int n = 0; n < 2; ++n)
                    acc[m][n] = __builtin_amdgcn_mfma_f32_16x16x32_f16(
                        av[m], bv[n], acc[m][n], 0, 0, 0);
        }
    }
    // transposed epilogue: Sp[kh][col][row], 4 consecutive f32 per lane
    float* outp = Sp + (size_t)kh * (NPAD * 512);
    #pragma unroll
    for (int m = 0; m < 2; ++m)
        #pragma unroll
        for (int n = 0; n < 2; ++n) {
            int col = col0 + wc * 32 + n * 16 + (lane & 15);
            int rowb = row0 + wr * 32 + m * 16 + (lane >> 4) * 4;
            #pragma unroll
            for (int j = 0; j < 4; ++j)
                outp[(size_t)col * 512 + rowb + j] = acc[m][n][j];
        }
}

// ================ mix: Aid[(band,o,b)][k] = scale * sum_i S*Wc ==========
__global__ __launch_bounds__(256) void k_mix(const float* __restrict__ Sp,
                                             const _Float16* __restrict__ Wc,
                                             _Float16* __restrict__ Aid) {
    const int startv[5] = {0,122,244,366,488};
    const int binsv[5]  = {123,123,123,123,485};
    const int n_ov[5]   = {25,25,25,25,28};
    const int dltv[5]   = {0,4,0,4,0};
    const int khv[5]    = {256,256,256,256,1024};
    const size_t wbase[5] = {0, 393600, 787200, 1180800, 1574400};  // halfs
    const size_t abase[5] = {0, 65536, 131072, 196608, 262144};     // halfs
    const int cum[6] = {0, 24600, 49200, 73800, 98400, 207040};
    int gid = blockIdx.x * 256 + threadIdx.x;
    if (gid >= 207040) return;
    int band = 0;
    while (gid >= cum[band + 1]) band++;
    int r = gid - cum[band];
    int b = r & 7;
    int t2 = r >> 3;
    int bins = binsv[band];
    int f_local = t2 % bins;
    int o_local = t2 / bins;
    int n_o = n_ov[band];
    int fg = startv[band] + f_local;

    const float* pr = Sp + (size_t)(2 * fg) * 512 + b * 64;   // re row, part0
    const float* pi = pr + 512;                                // im row, part0
    const float* qr = pr + NPAD * 512;                         // part1
    const float* qi = qr + 512;
    const uint4* wp4 = (const uint4*)((const unsigned*)Wc + (wbase[band] >> 1) +
                                      ((size_t)f_local * n_o + o_local) * 64);
    float xr = 0.f, xi = 0.f;
    #pragma unroll 4
    for (int ii = 0; ii < 16; ++ii) {
        float4 r0 = ((const float4*)pr)[ii];
        float4 r1 = ((const float4*)qr)[ii];
        float4 i0 = ((const float4*)pi)[ii];
        float4 i1 = ((const float4*)qi)[ii];
        uint4 wq = wp4[ii];
        float sr, si; float2 wv;
        sr = r0.x + r1.x; si = i0.x + i1.x; wv = h2f2(wq.x);
        xr = fmaf(sr, wv.x, xr); xr = fmaf(-si, wv.y, xr);
        xi = fmaf(sr, wv.y, xi); xi = fmaf(si, wv.x, xi);
        sr = r0.y + r1.y; si = i0.y + i1.y; wv = h2f2(wq.y);
        xr = fmaf(sr, wv.x, xr); xr = fmaf(-si, wv.y, xr);
        xi = fmaf(sr, wv.y, xi); xi = fmaf(si, wv.x, xi);
        sr = r0.z + r1.z; si = i0.z + i1.z; wv = h2f2(wq.z);
        xr = fmaf(sr, wv.x, xr); xr = fmaf(-si, wv.y, xr);
        xi = fmaf(sr, wv.y, xi); xi = fmaf(si, wv.x, xi);
        sr = r0.w + r1.w; si = i0.w + i1.w; wv = h2f2(wq.w);
        xr = fmaf(sr, wv.x, xr); xr = fmaf(-si, wv.y, xr);
        xi = fmaf(sr, wv.y, xi); xi = fmaf(si, wv.x, xi);
    }
    float scale = (fg == 0 ? 1.0f : 2.0f) / 3000.0f;
    size_t hoff = abase[band] + (size_t)(o_local * 8 + b) * khv[band] + 2 * f_local + dltv[band];
    ((unsigned*)Aid)[hoff >> 1] = f2h2(xr * scale, xi * scale);
}

// ================ idft MFMA GEMM (dbuf) + bias ==========================
__global__ __launch_bounds__(256) void k_idft_mm(const _Float16* __restrict__ Aid,
                                                 const _Float16* __restrict__ T,
                                                 const float* __restrict__ bias,
                                                 float* __restrict__ out) {
    __shared__ _Float16 As[2][64 * 64];
    __shared__ _Float16 Bs[2][64 * 64];
    const int n0v[5] = {0, 240, 488, 728, 976};
    const int n_ov[5] = {25,25,25,25,28};
    const size_t abase[5] = {0, 65536, 131072, 196608, 262144};
    int mt = blockIdx.y;                 // 0..19
    int band = mt >> 2;
    int row0b = (mt & 3) * 64;
    int col0 = blockIdx.x * 64;
    int Kh = (band < 4) ? 256 : 1024;
    int nkt = Kh / 64;
    const char* Ab = (const char*)Aid + abase[band] * 2;
    const char* Bb = (const char*)T + (size_t)n0v[band] * 2;
    int tid = threadIdx.x, wid = tid >> 6, lane = tid & 63;
    int wr = wid >> 1, wc = wid & 1;
    f32x4 acc[2][2] = {};

    auto stage = [&](int kt, int buf) {
        int k0 = kt * 64;
        #pragma unroll
        for (int it = 0; it < 2; ++it) {
            int cb = it * 256 + wid * 64;
            int cA = cb + lane;
            int ar = cA >> 3, cir = cA & 7;
            int cirs = cir ^ (ar & 7);       // swizzle in SOURCE addr
            GL16(Ab + ((size_t)(row0b + ar) * Kh + k0) * 2 + cirs * 16,
                 (char*)As[buf] + cb * 16);
            GL16(Bb + ((size_t)(col0 + ar) * TSTRIDE + k0) * 2 + cirs * 16,
                 (char*)Bs[buf] + cb * 16);
        }
    };
    stage(0, 0);
    for (int kt = 0; kt < nkt; ++kt) {
        int cur = kt & 1;
        asm volatile("s_waitcnt vmcnt(0)" ::: "memory");
        __syncthreads();
        if (kt + 1 < nkt) stage(kt + 1, cur ^ 1);
        #pragma unroll
        for (int ks = 0; ks < 2; ++ks) {
            f16x8 av[2], bv[2];
            #pragma unroll
            for (int m = 0; m < 2; ++m) {
                int r = wr * 32 + m * 16 + (lane & 15);
                int g = (ks * 4 + (lane >> 4)) ^ (r & 7);
                av[m] = *(const f16x8*)(As[cur] + r * 64 + g * 8);
            }
            #pragma unroll
            for (int n = 0; n < 2; ++n) {
                int r = wc * 32 + n * 16 + (lane & 15);
                int g = (ks * 4 + (lane >> 4)) ^ (r & 7);
                bv[n] = *(const f16x8*)(Bs[cur] + r * 64 + g * 8);
            }
            #pragma unroll
            for (int m = 0; m < 2; ++m)
                #pragma unroll
                for (int n = 0; n < 2; ++n)
                    acc[m][n] = __builtin_amdgcn_mfma_f32_16x16x32_f16(
                        av[m], bv[n], acc[m][n], 0, 0, 0);
        }
    }
    int n_o8 = n_ov[band] * 8;
    #pragma unroll
    for (int m = 0; m < 2; ++m)
        #pragma unroll
        for (int n = 0; n < 2; ++n) {
            int t = col0 + wc * 32 + n * 16 + (lane & 15);
            if (t >= TOUT) continue;
            int rowb = row0b + wr * 32 + m * 16 + (lane >> 4) * 4;
            #pragma unroll
            for (int j = 0; j < 4; ++j) {
                int prb = rowb + j;
                if (prb < n_o8) {
                    int o = band * 25 + (prb >> 3);
                    int b = prb & 7;
                    out[((size_t)b * COUT + o) * TOUT + t] = acc[m][n][j] + bias[o];
                }
            }
        }
}

extern "C" void kernel_launch(void* const* d_in, const int* in_sizes, int n_in,
                              void* d_out, int out_size, void* d_ws, size_t ws_size,
                              hipStream_t stream) {
    const float* sig  = (const float*)d_in[0];   // (8,64,3000) f32
    const float* w    = (const float*)d_in[1];   // (128,64,25) f32
    const float* bias = (const float*)d_in[2];   // (128,) f32
    float* out = (float*)d_out;
    char* wsb = (char*)d_ws;
    _Float16* A   = (_Float16*)(wsb + A_BYTE);
    _Float16* B   = (_Float16*)(wsb + B_BYTE);
    _Float16* T   = (_Float16*)(wsb + T_BYTE);
    _Float16* Wc  = (_Float16*)(wsb + WC_BYTE);
    float*    Sp  = (float*)(wsb + SP_BYTE);
    _Float16* Aid = (_Float16*)(wsb + AID_BYTE);

    k_prep   <<<dim3(8512),   256, 0, stream>>>(sig, w, wsb);
    k_dft_mm <<<dim3(31, 16), 256, 0, stream>>>(A, B, Sp);
    k_mix    <<<dim3(809),    256, 0, stream>>>(Sp, Wc, Aid);
    k_idft_mm<<<dim3(47, 20), 256, 0, stream>>>(Aid, T, bias, out);
}

// Round 7
// 80.688 us; speedup vs baseline: 6.5091x; 1.4384x over previous
//
#include <hip/hip_runtime.h>

#define L_SIG 3000
#define KPAD 3008           // 47*64
#define NB 8
#define CIN 64
#define COUT 128
#define KW 25
#define TOUT 2976
#define FMAXB 973
#define NCOLS 1946          // 2*FMAXB
#define NPAD 1984           // 31*64
#define TSTRIDE 2000        // T cols (halfs)
#define TROWS 3008          // 47*64

// ws byte layout (~45 MB; NO aliasing):
//  [0,        3080192)   A_fwd f16 [512][3008], pre-swizzled
//  [3145728, 15081472)   B_fwd f16 [1984][3008], pre-swizzled
//  [15728640,27760640)   T_idft f16 [3008][2000], linear
//  [28311552,34936832)   Wc f16 (3,312,640 halfs = 6,625,280 B)
//  [35651584,43778048)   S_part f32 [2][1984][512]
//  [44040192,45088768)   A_idft f16 (524,288 halfs)
#define A_BYTE    0
#define B_BYTE    3145728
#define T_BYTE    15728640
#define WC_BYTE   28311552
#define SP_BYTE   35651584
#define AID_BYTE  44040192

typedef _Float16 f16x8 __attribute__((ext_vector_type(8)));
typedef float f32x4 __attribute__((ext_vector_type(4)));

typedef __attribute__((address_space(1))) const unsigned GU;
typedef __attribute__((address_space(3))) unsigned LU;
#define GL16(g, l) __builtin_amdgcn_global_load_lds((GU*)(g), (LU*)(l), 16, 0, 0)

#define TWO_PI_OVER_L 0.00209439510239319549f

__device__ __forceinline__ float2 h2f2(unsigned u) {
    union { unsigned u; _Float16 h[2]; } p; p.u = u;
    return make_float2((float)p.h[0], (float)p.h[1]);
}
__device__ __forceinline__ unsigned f2h2(float a, float b) {
    union { unsigned u; _Float16 h[2]; } p;
    p.h[0] = (_Float16)a; p.h[1] = (_Float16)b; return p.u;
}

// ================= fused prep: gen_a | gen_b | gen_t | w_dft | zero =====
__global__ __launch_bounds__(256) void k_prep(const float* __restrict__ sig,
                                              const float* __restrict__ w,
                                              char* __restrict__ wsb) {
    __shared__ float wL[CIN * KW];
    int blk = blockIdx.x, tid = threadIdx.x;

    if (blk < 1024) {                        // ---- gen A_fwd (swizzled)
        _Float16* A = (_Float16*)(wsb + A_BYTE);
        int row = blk >> 1;
        int g = (blk & 1) * 256 + tid;
        if (g >= KPAD / 8) return;
        int gsw = (g & ~7) | ((g & 7) ^ (row & 7));
        union { _Float16 h[8]; uint4 u; } p;
        if (g < L_SIG / 8) {
            const float4* s4 = (const float4*)(sig + (size_t)row * L_SIG + g * 8);
            float4 a = s4[0], b = s4[1];
            p.h[0]=(_Float16)a.x; p.h[1]=(_Float16)a.y; p.h[2]=(_Float16)a.z; p.h[3]=(_Float16)a.w;
            p.h[4]=(_Float16)b.x; p.h[5]=(_Float16)b.y; p.h[6]=(_Float16)b.z; p.h[7]=(_Float16)b.w;
        } else p.u = make_uint4(0, 0, 0, 0);
        ((uint4*)A)[(size_t)row * (KPAD / 8) + gsw] = p.u;

    } else if (blk < 4992) {                 // ---- gen B_fwd (swizzled)
        _Float16* B = (_Float16*)(wsb + B_BYTE);
        int q = blk - 1024;
        int n = q >> 1;
        int g = (q & 1) * 256 + tid;
        if (g >= KPAD / 8) return;
        int f = n >> 1, c = n & 1;
        int gsw = (g & ~7) | ((g & 7) ^ (n & 7));
        union { _Float16 h[8]; uint4 u; } p;
        p.u = make_uint4(0, 0, 0, 0);
        if (f < FMAXB && g < L_SIG / 8) {
            int k0 = g * 8;
            int m0 = (int)(((long long)f * k0) % 3000);
            float s0, c0, sw, cw;
            __sincosf((float)m0 * TWO_PI_OVER_L, &s0, &c0);
            __sincosf((float)f * TWO_PI_OVER_L, &sw, &cw);
            float rr = c0, ri = -s0;         // e^{-i 2pi f k0/L}
            #pragma unroll
            for (int j = 0; j < 8; ++j) {
                p.h[j] = (_Float16)(c ? ri : rr);
                float nr = rr * cw + ri * sw;
                float ni = ri * cw - rr * sw;
                rr = nr; ri = ni;
            }
        }
        ((uint4*)B)[(size_t)n * (KPAD / 8) + gsw] = p.u;

    } else if (blk < 8000) {                 // ---- gen T_idft (linear)
        _Float16* T = (_Float16*)(wsb + T_BYTE);
        int t = blk - 4992;
        int g = tid;
        if (g >= TSTRIDE / 8) return;
        union { _Float16 h[8]; uint4 u; } p;
        p.u = make_uint4(0, 0, 0, 0);
        int f0 = g * 4;
        if (f0 < FMAXB) {
            int m0 = (int)(((long long)f0 * t) % 3000);
            float s0, c0, sw, cw;
            __sincosf((float)m0 * TWO_PI_OVER_L, &s0, &c0);
            __sincosf((float)t * TWO_PI_OVER_L, &sw, &cw);
            float rr = c0, ri = -s0;         // (cos, -sin) at f0
            #pragma unroll
            for (int j = 0; j < 4; ++j) {
                if (f0 + j < FMAXB) {
                    p.h[2 * j]     = (_Float16)rr;
                    p.h[2 * j + 1] = (_Float16)ri;
                }
                float nr = rr * cw + ri * sw;
                float ni = ri * cw - rr * sw;
                rr = nr; ri = ni;
            }
        }
        ((uint4*)T)[(size_t)t * (TSTRIDE / 8) + g] = p.u;

    } else if (blk < 8256) {                 // ---- weight DFT (conj)
        _Float16* Wc = (_Float16*)(wsb + WC_BYTE);
        const int startv[5] = {0,122,244,366,488};
        const int binsv[5]  = {123,123,123,123,485};
        const int n_ov[5]   = {25,25,25,25,28};
        const size_t wbase[5] = {0, 393600, 787200, 1180800, 1574400};  // halfs
        int q = blk - 8000;
        int o = q >> 1;
        int f = (q & 1) * 256 + tid;
        int band = min(o / 25, 4);
        int o_local = o - band * 25;
        int bins = binsv[band];
        const float* wrow = w + (size_t)o * CIN * KW;
        for (int k = tid; k < CIN * KW; k += 256) wL[k] = wrow[k];
        __syncthreads();
        if (f >= bins) return;
        int n_o = n_ov[band];
        int fg = startv[band] + f;
        float ws_, wc_;
        __sincosf((float)fg * TWO_PI_OVER_L, &ws_, &wc_);
        float wr = wc_, wi = ws_;            // conj roots: +sin
        unsigned* outp = (unsigned*)Wc + (wbase[band] >> 1) + ((size_t)f * n_o + o_local) * 64;
        for (int i = 0; i < CIN; ++i) {
            float ar = 0.f, ai = 0.f;
            float rr = 1.0f, ri = 0.0f;
            const float* wv = wL + i * KW;
            #pragma unroll
            for (int t = 0; t < KW; ++t) {
                float x = wv[t];
                ar = fmaf(x, rr, ar);
                ai = fmaf(x, ri, ai);
                float nr = fmaf(-ri, wi, rr * wr);
                float ni = fmaf( ri, wr, rr * wi);
                rr = nr; ri = ni;
            }
            outp[i] = f2h2(ar, ai);
        }

    } else {                                 // ---- zero A_idft
        uint4* Az = (uint4*)(wsb + AID_BYTE);
        int q = blk - 8256;
        Az[(size_t)q * 256 + tid] = make_uint4(0, 0, 0, 0);   // 65536 uint4
    }
}

// ================ fwd MFMA GEMM (split-K x2, dbuf): S_T = (A x B^T)^T ===
__global__ __launch_bounds__(256) void k_dft_mm(const _Float16* __restrict__ A,
                                                const _Float16* __restrict__ B,
                                                float* __restrict__ Sp) {
    __shared__ _Float16 As[2][64 * 64];
    __shared__ _Float16 Bs[2][64 * 64];
    int row0 = (blockIdx.y & 7) * 64;
    int kh   = blockIdx.y >> 3;
    int col0 = blockIdx.x * 64;
    int kt0  = kh ? 24 : 0;
    int nkt  = kh ? 23 : 24;
    int tid = threadIdx.x, wid = tid >> 6, lane = tid & 63;
    int wr = wid >> 1, wc = wid & 1;
    f32x4 acc[2][2] = {};

    auto stage = [&](int kt, int buf) {
        int k0 = (kt0 + kt) * 64;
        #pragma unroll
        for (int it = 0; it < 2; ++it) {
            int cb = it * 256 + wid * 64;
            int cA = cb + lane;
            int ar = cA >> 3, cir = cA & 7;
            GL16((const char*)A + ((size_t)(row0 + ar) * KPAD + k0) * 2 + cir * 16,
                 (char*)As[buf] + cb * 16);
            GL16((const char*)B + ((size_t)(col0 + ar) * KPAD + k0) * 2 + cir * 16,
                 (char*)Bs[buf] + cb * 16);
        }
    };
    stage(0, 0);
    for (int kt = 0; kt < nkt; ++kt) {
        int cur = kt & 1;
        asm volatile("s_waitcnt vmcnt(0)" ::: "memory");
        __syncthreads();
        if (kt + 1 < nkt) stage(kt + 1, cur ^ 1);
        #pragma unroll
        for (int ks = 0; ks < 2; ++ks) {
            f16x8 av[2], bv[2];
            #pragma unroll
            for (int m = 0; m < 2; ++m) {
                int r = wr * 32 + m * 16 + (lane & 15);
                int g = (ks * 4 + (lane >> 4)) ^ (r & 7);
                av[m] = *(const f16x8*)(As[cur] + r * 64 + g * 8);
            }
            #pragma unroll
            for (int n = 0; n < 2; ++n) {
                int r = wc * 32 + n * 16 + (lane & 15);
                int g = (ks * 4 + (lane >> 4)) ^ (r & 7);
                bv[n] = *(const f16x8*)(Bs[cur] + r * 64 + g * 8);
            }
            #pragma unroll
            for (int m = 0; m < 2; ++m)
                #pragma unroll
                for (int n = 0; n < 2; ++n)
                    acc[m][n] = __builtin_amdgcn_mfma_f32_16x16x32_f16(
                        av[m], bv[n], acc[m][n], 0, 0, 0);
        }
    }
    float* outp = Sp + (size_t)kh * (NPAD * 512);
    #pragma unroll
    for (int m = 0; m < 2; ++m)
        #pragma unroll
        for (int n = 0; n < 2; ++n) {
            int col = col0 + wc * 32 + n * 16 + (lane & 15);
            int rowb = row0 + wr * 32 + m * 16 + (lane >> 4) * 4;
            #pragma unroll
            for (int j = 0; j < 4; ++j)
                outp[(size_t)col * 512 + rowb + j] = acc[m][n][j];
        }
}

// ================ mix v2: one block per (band, f_local) bin =============
// Stage the bin's Sp columns once (re+im, parts summed) into LDS, then
// thread (o_local, b) does the 64-long complex dot.
__global__ __launch_bounds__(256) void k_mix(const float* __restrict__ Sp,
                                             const _Float16* __restrict__ Wc,
                                             _Float16* __restrict__ Aid) {
    __shared__ float s_re[8 * 72];           // [b][i], pitch 72 (2-way alias = free)
    __shared__ float s_im[8 * 72];
    const int startv[5] = {0,122,244,366,488};
    const int n_ov[5]   = {25,25,25,25,28};
    const int dltv[5]   = {0,4,0,4,0};
    const int khv[5]    = {256,256,256,256,1024};
    const size_t wbase[5] = {0, 393600, 787200, 1180800, 1574400};  // halfs
    const size_t abase[5] = {0, 65536, 131072, 196608, 262144};     // halfs
    const int cumb[6] = {0, 123, 246, 369, 492, 977};
    int blk = blockIdx.x, tid = threadIdx.x;
    int band = 0;
    while (blk >= cumb[band + 1]) band++;
    int f_local = blk - cumb[band];
    int fg = startv[band] + f_local;

    // stage: re col = Sp[.][2fg][.], im col = Sp[.][2fg+1][.]; sum parts
    const float* p0 = Sp + (size_t)(2 * fg) * 512;      // part0 re col
    const float* p1 = p0 + (size_t)NPAD * 512;          // part1 re col
    #pragma unroll
    for (int e = 0; e < 2; ++e) {
        int row = tid + e * 256;                         // b*64+i
        int b = row >> 6, i = row & 63;
        s_re[b * 72 + i] = p0[row] + p1[row];
        s_im[b * 72 + i] = p0[512 + row] + p1[512 + row];
    }
    __syncthreads();

    int o_local = tid >> 3, b = tid & 7;
    int n_o = n_ov[band];
    if (o_local >= n_o) return;
    const uint4* wp4 = (const uint4*)((const unsigned*)Wc + (wbase[band] >> 1) +
                                      ((size_t)f_local * n_o + o_local) * 64);
    const float* lre = s_re + b * 72;
    const float* lim = s_im + b * 72;
    float xr = 0.f, xi = 0.f;
    #pragma unroll
    for (int ii = 0; ii < 16; ++ii) {
        float4 r4 = *(const float4*)(lre + ii * 4);
        float4 i4 = *(const float4*)(lim + ii * 4);
        uint4 wq = wp4[ii];
        float2 wv;
        wv = h2f2(wq.x);
        xr = fmaf(r4.x, wv.x, xr); xr = fmaf(-i4.x, wv.y, xr);
        xi = fmaf(r4.x, wv.y, xi); xi = fmaf( i4.x, wv.x, xi);
        wv = h2f2(wq.y);
        xr = fmaf(r4.y, wv.x, xr); xr = fmaf(-i4.y, wv.y, xr);
        xi = fmaf(r4.y, wv.y, xi); xi = fmaf( i4.y, wv.x, xi);
        wv = h2f2(wq.z);
        xr = fmaf(r4.z, wv.x, xr); xr = fmaf(-i4.z, wv.y, xr);
        xi = fmaf(r4.z, wv.y, xi); xi = fmaf( i4.z, wv.x, xi);
        wv = h2f2(wq.w);
        xr = fmaf(r4.w, wv.x, xr); xr = fmaf(-i4.w, wv.y, xr);
        xi = fmaf(r4.w, wv.y, xi); xi = fmaf( i4.w, wv.x, xi);
    }
    float scale = (fg == 0 ? 1.0f : 2.0f) / 3000.0f;
    size_t hoff = abase[band] + (size_t)(o_local * 8 + b) * khv[band] + 2 * f_local + dltv[band];
    ((unsigned*)Aid)[hoff >> 1] = f2h2(xr * scale, xi * scale);
}

// ================ idft MFMA GEMM (dbuf) + bias ==========================
__global__ __launch_bounds__(256) void k_idft_mm(const _Float16* __restrict__ Aid,
                                                 const _Float16* __restrict__ T,
                                                 const float* __restrict__ bias,
                                                 float* __restrict__ out) {
    __shared__ _Float16 As[2][64 * 64];
    __shared__ _Float16 Bs[2][64 * 64];
    const int n0v[5] = {0, 240, 488, 728, 976};
    const int n_ov[5] = {25,25,25,25,28};
    const size_t abase[5] = {0, 65536, 131072, 196608, 262144};
    int mt = blockIdx.y;                 // 0..19
    int band = mt >> 2;
    int row0b = (mt & 3) * 64;
    int col0 = blockIdx.x * 64;
    int Kh = (band < 4) ? 256 : 1024;
    int nkt = Kh / 64;
    const char* Ab = (const char*)Aid + abase[band] * 2;
    const char* Bb = (const char*)T + (size_t)n0v[band] * 2;
    int tid = threadIdx.x, wid = tid >> 6, lane = tid & 63;
    int wr = wid >> 1, wc = wid & 1;
    f32x4 acc[2][2] = {};

    auto stage = [&](int kt, int buf) {
        int k0 = kt * 64;
        #pragma unroll
        for (int it = 0; it < 2; ++it) {
            int cb = it * 256 + wid * 64;
            int cA = cb + lane;
            int ar = cA >> 3, cir = cA & 7;
            int cirs = cir ^ (ar & 7);       // swizzle in SOURCE addr
            GL16(Ab + ((size_t)(row0b + ar) * Kh + k0) * 2 + cirs * 16,
                 (char*)As[buf] + cb * 16);
            GL16(Bb + ((size_t)(col0 + ar) * TSTRIDE + k0) * 2 + cirs * 16,
                 (char*)Bs[buf] + cb * 16);
        }
    };
    stage(0, 0);
    for (int kt = 0; kt < nkt; ++kt) {
        int cur = kt & 1;
        asm volatile("s_waitcnt vmcnt(0)" ::: "memory");
        __syncthreads();
        if (kt + 1 < nkt) stage(kt + 1, cur ^ 1);
        #pragma unroll
        for (int ks = 0; ks < 2; ++ks) {
            f16x8 av[2], bv[2];
            #pragma unroll
            for (int m = 0; m < 2; ++m) {
                int r = wr * 32 + m * 16 + (lane & 15);
                int g = (ks * 4 + (lane >> 4)) ^ (r & 7);
                av[m] = *(const f16x8*)(As[cur] + r * 64 + g * 8);
            }
            #pragma unroll
            for (int n = 0; n < 2; ++n) {
                int r = wc * 32 + n * 16 + (lane & 15);
                int g = (ks * 4 + (lane >> 4)) ^ (r & 7);
                bv[n] = *(const f16x8*)(Bs[cur] + r * 64 + g * 8);
            }
            #pragma unroll
            for (int m = 0; m < 2; ++m)
                #pragma unroll
                for (int n = 0; n < 2; ++n)
                    acc[m][n] = __builtin_amdgcn_mfma_f32_16x16x32_f16(
                        av[m], bv[n], acc[m][n], 0, 0, 0);
        }
    }
    int n_o8 = n_ov[band] * 8;
    #pragma unroll
    for (int m = 0; m < 2; ++m)
        #pragma unroll
        for (int n = 0; n < 2; ++n) {
            int t = col0 + wc * 32 + n * 16 + (lane & 15);
            if (t >= TOUT) continue;
            int rowb = row0b + wr * 32 + m * 16 + (lane >> 4) * 4;
            #pragma unroll
            for (int j = 0; j < 4; ++j) {
                int prb = rowb + j;
                if (prb < n_o8) {
                    int o = band * 25 + (prb >> 3);
                    int b = prb & 7;
                    out[((size_t)b * COUT + o) * TOUT + t] = acc[m][n][j] + bias[o];
                }
            }
        }
}

extern "C" void kernel_launch(void* const* d_in, const int* in_sizes, int n_in,
                              void* d_out, int out_size, void* d_ws, size_t ws_size,
                              hipStream_t stream) {
    const float* sig  = (const float*)d_in[0];   // (8,64,3000) f32
    const float* w    = (const float*)d_in[1];   // (128,64,25) f32
    const float* bias = (const float*)d_in[2];   // (128,) f32
    float* out = (float*)d_out;
    char* wsb = (char*)d_ws;
    _Float16* A   = (_Float16*)(wsb + A_BYTE);
    _Float16* B   = (_Float16*)(wsb + B_BYTE);
    _Float16* T   = (_Float16*)(wsb + T_BYTE);
    _Float16* Wc  = (_Float16*)(wsb + WC_BYTE);
    float*    Sp  = (float*)(wsb + SP_BYTE);
    _Float16* Aid = (_Float16*)(wsb + AID_BYTE);

    k_prep   <<<dim3(8512),   256, 0, stream>>>(sig, w, wsb);
    k_dft_mm <<<dim3(31, 16), 256, 0, stream>>>(A, B, Sp);
    k_mix    <<<dim3(977),    256, 0, stream>>>(Sp, Wc, Aid);
    k_idft_mm<<<dim3(47, 20), 256, 0, stream>>>(Aid, T, bias, out);
}